// Round 7
// baseline (251.352 us; speedup 1.0000x reference)
//
#include <hip/hip_runtime.h>

// 9x9 box-sum (R=4), zero-padded, 128 fp32 planes of 512x512.
// R7 = R6 with __launch_bounds__(256, 4). Evidence across R0-R6: measured
// occupancy tracks the launch_bounds 2nd arg ((,8)->77%, (,4)->37-51%,
// (,2)->18-24%), NOT VGPR count -- at VGPR=84 HW could fit 6 waves/SIMD but
// only ~2 are resident under (,2). The R6 body (branch-free, 2 loads/row-step,
// dense 1KB loads/stores, DPP horizontal sums) is latency-exposed at 2
// waves/SIMD (~2075 cy/row-step vs ~240 cy VALU). Budget at (,4) is 128 VGPRs
// >= the 84 this body needs, so no spill expected (tripwire: WRITE_SIZE must
// stay == 131072 KB).
//
// Structure (from R5/R6):
// - lane l owns cols A=4l..4l+3 and B=256+4l..256+4l+3 (contiguous 1KB/wave).
// - horizontal 9-sum via DPP wave shifts (zero fill == image edge pad), A<->B
//   seams patched with readlane broadcasts + per-lane selects.
// - branch-free row handling (clamp + 0/1 mask) -> single basic block.
// - ring of 8: out = vsum8 + h_new; vsum8' = out - h_old.
// - nontemporal float4 output stores.

#define W   512
#define RR  16          // output rows per wave strip
#define NSTRIP (W / RR) // 32

typedef float vfloat4 __attribute__((ext_vector_type(4)));

__device__ __forceinline__ float4 ld4(const float* p) { return *(const float4*)p; }
__device__ __forceinline__ float4 add4(float4 a, float4 b) {
    return make_float4(a.x + b.x, a.y + b.y, a.z + b.z, a.w + b.w);
}
__device__ __forceinline__ float4 sub4(float4 a, float4 b) {
    return make_float4(a.x - b.x, a.y - b.y, a.z - b.z, a.w - b.w);
}
__device__ __forceinline__ float4 mul4s(float4 a, float m) {
    return make_float4(a.x * m, a.y * m, a.z * m, a.w * m);
}
__device__ __forceinline__ void st4_nt(float* p, float4 v) {
    vfloat4 q = { v.x, v.y, v.z, v.w };
    __builtin_nontemporal_store(q, (vfloat4*)p);
}

// DPP wave-wide lane shifts, zero fill at the boundary lane.
__device__ __forceinline__ float lane_shr1(float x) {   // lane i <- lane i-1; lane 0 <- 0
    return __int_as_float(__builtin_amdgcn_update_dpp(
        0, __float_as_int(x), 0x138 /*WAVE_SHR1*/, 0xF, 0xF, true));
}
__device__ __forceinline__ float lane_shl1(float x) {   // lane i <- lane i+1; lane 63 <- 0
    return __int_as_float(__builtin_amdgcn_update_dpp(
        0, __float_as_int(x), 0x130 /*WAVE_SHL1*/, 0xF, 0xF, true));
}
__device__ __forceinline__ float4 lane_shr1_4(float4 v) {
    return make_float4(lane_shr1(v.x), lane_shr1(v.y), lane_shr1(v.z), lane_shr1(v.w));
}
__device__ __forceinline__ float4 lane_shl1_4(float4 v) {
    return make_float4(lane_shl1(v.x), lane_shl1(v.y), lane_shl1(v.z), lane_shl1(v.w));
}
__device__ __forceinline__ float bcast(float x, int lane) {
    return __int_as_float(__builtin_amdgcn_readlane(__float_as_int(x), lane));
}

__global__ __launch_bounds__(256, 4) void boxfilter9(const float* __restrict__ in,
                                                     float* __restrict__ out) {
    const int t     = threadIdx.x;
    const int l     = t & 63;                       // lane
    const int wid   = t >> 6;                       // wave in block
    const int unit  = blockIdx.x * 4 + wid;         // img*NSTRIP + strip (wave-uniform)
    const int img   = unit >> 5;                    // / NSTRIP
    const int strip = unit & (NSTRIP - 1);

    const float* __restrict__ inp  = in  + (size_t)img * W * W;
    float* __restrict__       outp = out + (size_t)img * W * W;
    const int y0 = strip * RR;
    const int cA = l << 2;                          // group A: cols 4l..4l+3
    const int cB = 256 + (l << 2);                  // group B: cols 256+4l..

    // 9-wide horizontal running sum from prev/own/next float4
    auto hchain = [](float4 p, float4 v, float4 n) -> float4 {
        float sp = (p.x + p.y) + (p.z + p.w);
        float sv = (v.x + v.y) + (v.z + v.w);
        float4 h;
        h.x = (sp + sv) + n.x;
        h.y = h.x - p.x + n.y;
        h.z = h.y - p.y + n.z;
        h.w = h.z - p.z + n.w;
        return h;
    };

    // horizontal 9-sums for row y (branch-free: clamp row, 0/1 mask for pad rows)
    auto compute_h = [&](int y, float4& hA, float4& hB) {
        int yc = y < 0 ? 0 : (y > W - 1 ? W - 1 : y);
        float m = (y == yc) ? 1.0f : 0.0f;          // wave-uniform
        const float* row = inp + yc * W;
        float4 vA = mul4s(ld4(row + cA), m);
        float4 vB = mul4s(ld4(row + cB), m);
        float4 pA = lane_shr1_4(vA);                // lane0 -> 0 == image left edge
        float4 nA = lane_shl1_4(vA);                // lane63 needs vB@lane0 (seam)
        float4 pB = lane_shr1_4(vB);                // lane0 needs vA@lane63 (seam)
        float4 nB = lane_shl1_4(vB);                // lane63 -> 0 == image right edge
        // seam fixups via uniform broadcasts + per-lane select
        float a63x = bcast(vA.x, 63), a63y = bcast(vA.y, 63),
              a63z = bcast(vA.z, 63), a63w = bcast(vA.w, 63);
        float b0x  = bcast(vB.x, 0),  b0y  = bcast(vB.y, 0),
              b0z  = bcast(vB.z, 0),  b0w  = bcast(vB.w, 0);
        pB.x = (l == 0) ? a63x : pB.x;
        pB.y = (l == 0) ? a63y : pB.y;
        pB.z = (l == 0) ? a63z : pB.z;
        pB.w = (l == 0) ? a63w : pB.w;
        nA.x = (l == 63) ? b0x : nA.x;
        nA.y = (l == 63) ? b0y : nA.y;
        nA.z = (l == 63) ? b0z : nA.z;
        nA.w = (l == 63) ? b0w : nA.w;
        hA = hchain(pA, vA, nA);
        hB = hchain(pB, vB, nB);
    };

    // prologue: ring[k] = h(y0-4+k), k=0..7; vsum8 = sum of those 8 rows
    float4 ringA[8], ringB[8];
    float4 vsA = make_float4(0, 0, 0, 0), vsB = make_float4(0, 0, 0, 0);
    #pragma unroll
    for (int k = 0; k < 8; ++k) {
        compute_h(y0 - 4 + k, ringA[k], ringB[k]);
        vsA = add4(vsA, ringA[k]);
        vsB = add4(vsB, ringB[k]);
    }

    // main: out(y) = vsum8 + h(y+4); vsum8' = out - h(y-4); slot (i&7) is both
    // the departing h(y-4) and the landing spot for h(y+4) (read before write).
    #pragma unroll
    for (int i = 0; i < RR; ++i) {
        float4 hA, hB;
        compute_h(y0 + 4 + i, hA, hB);
        float4 oA = add4(vsA, hA);
        float4 oB = add4(vsB, hB);
        float* orow = outp + (size_t)(y0 + i) * W;
        st4_nt(orow + cA, oA);
        st4_nt(orow + cB, oB);
        vsA = sub4(oA, ringA[i & 7]);
        vsB = sub4(oB, ringB[i & 7]);
        ringA[i & 7] = hA;
        ringB[i & 7] = hB;
    }
}

extern "C" void kernel_launch(void* const* d_in, const int* in_sizes, int n_in,
                              void* d_out, int out_size, void* d_ws, size_t ws_size,
                              hipStream_t stream) {
    const float* x = (const float*)d_in[0];
    float* y = (float*)d_out;
    // 128 images x 32 strips = 4096 wave-units, 4 per 256-thread block
    dim3 grid(128 * NSTRIP / 4);
    dim3 block(256);
    boxfilter9<<<grid, block, 0, stream>>>(x, y);
}